// Round 10
// baseline (583.412 us; speedup 1.0000x reference)
//
#include <hip/hip_runtime.h>
#include <cstdint>
#include <cstddef>

// Problem constants (from reference): IN=512, H=8, C=8, HID=64, OUT=64
#define LEAKY 0.2f
#define NEG_INF -3.402823466e38f
static const int CHUNK = 2048;   // scan chunk per block (256 thr * 8)

typedef __attribute__((ext_vector_type(8))) short short8;
typedef __attribute__((ext_vector_type(4))) float floatx4;

__device__ __forceinline__ unsigned short f2bf(float f) {   // RNE float->bf16
    unsigned u = __float_as_uint(f);
    u += 0x7fffu + ((u >> 16) & 1u);
    return (unsigned short)(u >> 16);
}
__device__ __forceinline__ float bf2f(unsigned short u) {
    return __uint_as_float(((unsigned)u) << 16);
}
__device__ __forceinline__ float bflo(unsigned u) { return __uint_as_float(u << 16); }
__device__ __forceinline__ float bfhi(unsigned u) { return __uint_as_float(u & 0xffff0000u); }

// ---------------------------------------------------------------- misc init: W1t prep + deg8 zero (merged dispatch)
__global__ __launch_bounds__(256) void k_misc(const float* __restrict__ W1, unsigned short* __restrict__ W1t,
                                              int* __restrict__ deg8, int Nn) {
    int i = blockIdx.x * 256 + threadIdx.x;
    if (i < 64 * 512) {
        int n = i >> 9, k = i & 511;
        W1t[i] = f2bf(W1[k * 64 + n]);           // coalesced write, cached read
    }
    if (i < 8 * Nn) deg8[i] = 0;                 // privatized histograms
}

// ---------------------------------------------------------------- MEGA1: gemm1 (blocks [0,G1)) || edge count (blocks [G1,G1+1024))
// R8 structure exactly (best measured: 558.8 total; R9's 512-thread variant
// regressed +13us). gemm1: h1bf[M,64] = bf16(x[M,512] @ W1) + fused sc1.
// As+Bs LDS double-buffered, load-early/LDS-write-late, ONE barrier per K-step.
// count: single-pass 8-way privatized histograms deg8[cb&7][d] (XCD-local).
__global__ __launch_bounds__(256) void k_mega1(const float* __restrict__ A, const unsigned short* __restrict__ W1t,
                                               unsigned short* __restrict__ C,
                                               const float* __restrict__ as1, const float* __restrict__ ad1,
                                               float* __restrict__ scs, float* __restrict__ scd, int M,
                                               const int* __restrict__ ei, int* __restrict__ deg8, int E, int G1) {
    __shared__ __align__(16) unsigned short As[2][128][40];   // 2 x 10KB, 80B row stride
    __shared__ __align__(16) unsigned short Bs[2][64][40];    // 2 x  5KB

    if ((int)blockIdx.x >= G1) {
        // ---- edge-count branch: one pass, privatized histogram
        int cb = blockIdx.x - G1;                // 0..1023
        int nthr = 1024 * 256;
        int tid = cb * 256 + threadIdx.x;
        int* mydeg = deg8 + (size_t)(cb & 7) * M;
        for (int e = tid; e < E; e += nthr) {
            int d = ei[E + e];
            atomicAdd(&mydeg[d], 1);
        }
        return;
    }

    // ---- GEMM branch
    int t = threadIdx.x;
    int w = t >> 6, l = t & 63;
    int quad = l >> 4, lm = l & 15;
    int row0 = blockIdx.x * 128;

    // staging addresses (fixed per thread)
    const float* aptr[4];
#pragma unroll
    for (int j = 0; j < 4; ++j) {
        int f = t + 256 * j;
        int r = f >> 3, c4 = f & 7;
        int rg = row0 + r; if (rg >= M) rg = M - 1;
        aptr[j] = A + (size_t)rg * 512 + c4 * 4;
    }
    int bn = t >> 2, bseg = t & 3;
    const unsigned short* bptr = W1t + (size_t)bn * 512 + bseg * 8;
    int sr = t >> 3, sc4 = t & 7;          // LDS store coords

    floatx4 acc[2][4] = {};
    float4 va[4];
    uint4 vb;

    // prologue: tile 0 -> regs -> LDS[0]
#pragma unroll
    for (int j = 0; j < 4; ++j) va[j] = *(const float4*)(aptr[j] + 0);
    vb = *(const uint4*)(bptr + 0);
#pragma unroll
    for (int j = 0; j < 4; ++j) {
        ushort4 b; b.x = f2bf(va[j].x); b.y = f2bf(va[j].y); b.z = f2bf(va[j].z); b.w = f2bf(va[j].w);
        *(ushort4*)&As[0][sr + 32 * j][sc4 * 4] = b;
    }
    *(uint4*)&Bs[0][bn][bseg * 8] = vb;
    __syncthreads();

#pragma unroll
    for (int kt = 0; kt < 16; ++kt) {
        int cur = kt & 1;
        if (kt < 15) {                       // issue next-tile global loads EARLY
            int k0 = (kt + 1) * 32;
#pragma unroll
            for (int j = 0; j < 4; ++j) va[j] = *(const float4*)(aptr[j] + k0);
            vb = *(const uint4*)(bptr + k0);
        }

        short8 af[2], bfm[4];
#pragma unroll
        for (int tm = 0; tm < 2; ++tm) {
            int m = w * 32 + tm * 16 + lm;
            af[tm] = *(const short8*)&As[cur][m][quad * 8];
        }
#pragma unroll
        for (int tn = 0; tn < 4; ++tn) {
            int n = tn * 16 + lm;
            bfm[tn] = *(const short8*)&Bs[cur][n][quad * 8];
        }
#pragma unroll
        for (int tm = 0; tm < 2; ++tm)
#pragma unroll
            for (int tn = 0; tn < 4; ++tn)
                acc[tm][tn] = __builtin_amdgcn_mfma_f32_16x16x32_bf16(af[tm], bfm[tn], acc[tm][tn], 0, 0, 0);

        if (kt < 15) {                       // LDS-write LATE (after MFMA issue)
            int nxt = cur ^ 1;
#pragma unroll
            for (int j = 0; j < 4; ++j) {
                ushort4 b; b.x = f2bf(va[j].x); b.y = f2bf(va[j].y); b.z = f2bf(va[j].z); b.w = f2bf(va[j].w);
                *(ushort4*)&As[nxt][sr + 32 * j][sc4 * 4] = b;
            }
            *(uint4*)&Bs[nxt][bn][bseg * 8] = vb;
        }
        __syncthreads();                     // single barrier per K-step
    }

    // per-lane attention-vector entries: col = tn*16+lm, head = col>>3 = tn*2 + (lm>>3)
    float as_l[4], ad_l[4];
#pragma unroll
    for (int tn = 0; tn < 4; ++tn) { as_l[tn] = as1[tn * 16 + lm]; ad_l[tn] = ad1[tn * 16 + lm]; }
    int hbase = (l >> 3) & 1;

    // epilogue: C/D layout col=lane&15, row=quad*4+reg ; emit bf16 + scores
#pragma unroll
    for (int tm = 0; tm < 2; ++tm) {
#pragma unroll
        for (int r = 0; r < 4; ++r) {
            int row = row0 + w * 32 + tm * 16 + quad * 4 + r;
            if (row < M) {
#pragma unroll
                for (int tn = 0; tn < 4; ++tn)
                    C[(size_t)row * 64 + tn * 16 + lm] = f2bf(acc[tm][tn][r]);
                // fused half-scores: per-head dot over the 8 channels (reduce lm&7 axis)
                float ps[4], pd[4];
#pragma unroll
                for (int tn = 0; tn < 4; ++tn) {
                    ps[tn] = acc[tm][tn][r] * as_l[tn];
                    pd[tn] = acc[tm][tn][r] * ad_l[tn];
                }
#pragma unroll
                for (int o = 1; o < 8; o <<= 1) {
#pragma unroll
                    for (int tn = 0; tn < 4; ++tn) {
                        ps[tn] += __shfl_xor(ps[tn], o);
                        pd[tn] += __shfl_xor(pd[tn], o);
                    }
                }
                if ((l & 7) == 0) {
#pragma unroll
                    for (int tn = 0; tn < 4; ++tn) {
                        scs[(size_t)row * 8 + tn * 2 + hbase] = ps[tn];
                        scd[(size_t)row * 8 + tn * 2 + hbase] = pd[tn];
                    }
                }
            }
        }
    }
}

// fold deg8 -> deg (+1 self-loop), produce block sums
__global__ __launch_bounds__(256) void k_scan1(const int* __restrict__ deg8, int* __restrict__ deg,
                                               int* __restrict__ bsum, int Nn) {
    __shared__ int sm[256];
    int b = blockIdx.x, t = threadIdx.x;
    int s = 0;
    int i0 = b * CHUNK + t * 8;
#pragma unroll
    for (int j = 0; j < 8; ++j) {
        int i = i0 + j;
        if (i < Nn) {
            int d = 1;
#pragma unroll
            for (int p = 0; p < 8; ++p) d += deg8[(size_t)p * Nn + i];
            deg[i] = d;
            s += d;
        }
    }
    sm[t] = s;
    __syncthreads();
    for (int o = 128; o; o >>= 1) { if (t < o) sm[t] += sm[t + o]; __syncthreads(); }
    if (t == 0) bsum[b] = sm[0];
}

// scan3: indptr + per-partition cursor bases + self-loop CSR entries.
// cursor8[p][i] = indptr[i] + 1 + sum_{q<p} deg8[q][i]  (self-loop at slot indptr[i])
__global__ __launch_bounds__(256) void k_scan3(const int* __restrict__ deg, const int* __restrict__ deg8,
                                               const int* __restrict__ bsum,
                                               int* __restrict__ indptr, int* __restrict__ cursor8,
                                               int* __restrict__ csr, int Nn, int B) {
    __shared__ int wsum[4];
    int b = blockIdx.x, t = threadIdx.x, lane = t & 63, w = t >> 6;

    int vb = (lane < B) ? bsum[lane] : 0;
    int incb = vb;
#pragma unroll
    for (int o = 1; o < 64; o <<= 1) { int u = __shfl_up(incb, o); if (lane >= o) incb += u; }
    int bpre_b = __shfl(incb - vb, b);       // exclusive prefix at block b

    int i0 = b * CHUNK + t * 8;
    int d[8]; int s = 0;
#pragma unroll
    for (int j = 0; j < 8; ++j) { int i = i0 + j; d[j] = (i < Nn) ? deg[i] : 0; s += d[j]; }
    int inc = s;
#pragma unroll
    for (int o = 1; o < 64; o <<= 1) { int u = __shfl_up(inc, o); if (lane >= o) inc += u; }
    if (lane == 63) wsum[w] = inc;
    __syncthreads();
    int wofs = 0;
    for (int k = 0; k < w; ++k) wofs += wsum[k];
    int base = bpre_b + wofs + (inc - s);
    int run = 0;
#pragma unroll
    for (int j = 0; j < 8; ++j) {
        int i = i0 + j;
        if (i < Nn) {
            int v = base + run;
            indptr[i] = v;
            csr[v] = i;                      // self-loop occupies first slot
            int cb2 = v + 1;
#pragma unroll
            for (int p = 0; p < 8; ++p) {
                cursor8[(size_t)p * Nn + i] = cb2;
                cb2 += deg8[(size_t)p * Nn + i];
            }
            run += d[j];
            if (i == Nn - 1) indptr[Nn] = v + d[j];
        }
    }
}

// single-pass privatized fill: same edge->block mapping as the count branch,
// so edge e uses cursor copy (block(e)&7) whose range was sized by deg8[p][d].
// Atomics stay XCD-local; ei read ONCE (old fill re-scanned dst 8x = 54MB).
__global__ __launch_bounds__(256) void k_fill_priv(const int* __restrict__ ei, int* __restrict__ cursor8,
                                                   int* __restrict__ csr, int E, int Nn) {
    int cb = blockIdx.x;                     // 0..1023
    int nthr = 1024 * 256;
    int tid = cb * 256 + threadIdx.x;
    int* mycur = cursor8 + (size_t)(cb & 7) * Nn;
    for (int e = tid; e < E; e += nthr) {
        int d = ei[E + e];
        int s = ei[e];
        int slot = atomicAdd(&mycur[d], 1);
        csr[slot] = s;
    }
}

// ---------------------------------------------------------------- SGEMM Cbf[M,64] = bf16(A[M,K] @ B[K,64]) (fp32 math, conv2)
// + fused conv2 half-scores from fp32 accumulators.
template <int KB>
__global__ __launch_bounds__(256) void gemm_n64(const float* __restrict__ A, const float* __restrict__ B,
                                                unsigned short* __restrict__ C,
                                                const float* __restrict__ as2, const float* __restrict__ ad2,
                                                float* __restrict__ sc2s, float* __restrict__ sc2d,
                                                int M, int K) {
    __shared__ float As[KB][68];
    __shared__ float Bs[KB][68];
    int tid = threadIdx.x;
    int row0 = blockIdx.x * 64;
    int tx = tid & 15, ty = tid >> 4;
    float acc[4][4] = {};
    for (int k0 = 0; k0 < K; k0 += KB) {
#pragma unroll
        for (int j = 0; j < (64 * KB) / (256 * 4); ++j) {
            int f = tid + 256 * j;
            int r = f / (KB / 4);
            int c4 = f % (KB / 4);
            int rg = row0 + r; if (rg >= M) rg = M - 1;
            float4 v = *(const float4*)(A + (size_t)rg * K + k0 + c4 * 4);
            As[c4 * 4 + 0][r] = v.x; As[c4 * 4 + 1][r] = v.y;
            As[c4 * 4 + 2][r] = v.z; As[c4 * 4 + 3][r] = v.w;
        }
#pragma unroll
        for (int j = 0; j < (KB * 64) / (256 * 4); ++j) {
            int f = tid + 256 * j;
            int kk = f / 16, c4 = f % 16;
            *(float4*)&Bs[kk][c4 * 4] = *(const float4*)(B + (size_t)(k0 + kk) * 64 + c4 * 4);
        }
        __syncthreads();
#pragma unroll
        for (int kk = 0; kk < KB; ++kk) {
            float4 a = *(const float4*)&As[kk][ty * 4];
            float4 b = *(const float4*)&Bs[kk][tx * 4];
            float av[4] = {a.x, a.y, a.z, a.w};
            float bv[4] = {b.x, b.y, b.z, b.w};
#pragma unroll
            for (int i = 0; i < 4; ++i)
#pragma unroll
                for (int j = 0; j < 4; ++j) acc[i][j] += av[i] * bv[j];
        }
        __syncthreads();
    }
    float as_l[4], ad_l[4];
#pragma unroll
    for (int j = 0; j < 4; ++j) { as_l[j] = as2[tx * 4 + j]; ad_l[j] = ad2[tx * 4 + j]; }
#pragma unroll
    for (int i = 0; i < 4; ++i) {
        int rg = row0 + ty * 4 + i;
        if (rg < M) {
            ushort4 b; b.x = f2bf(acc[i][0]); b.y = f2bf(acc[i][1]);
            b.z = f2bf(acc[i][2]); b.w = f2bf(acc[i][3]);
            *(ushort4*)(C + (size_t)rg * 64 + tx * 4) = b;
            // fused full-row score dot: reduce over tx axis (lane bits 0..3)
            float ps = acc[i][0] * as_l[0] + acc[i][1] * as_l[1] + acc[i][2] * as_l[2] + acc[i][3] * as_l[3];
            float pd = acc[i][0] * ad_l[0] + acc[i][1] * ad_l[1] + acc[i][2] * ad_l[2] + acc[i][3] * ad_l[3];
#pragma unroll
            for (int o = 1; o < 16; o <<= 1) { ps += __shfl_xor(ps, o); pd += __shfl_xor(pd, o); }
            if (tx == 0) { sc2s[rg] = ps; sc2d[rg] = pd; }
        }
    }
}

// ---------------------------------------------------------------- conv1 aggregation (8 heads x 8 ch) -> elu -> x2
// One wave per node. Lane l: edge-in-batch g=l>>3, head/channel-octet h8=l&7.
// NO-MAX softmax (bounded logits). R3 flat form (batched MLP measured slower twice).
__global__ __launch_bounds__(256) void k_agg1(const unsigned short* __restrict__ h1, const float* __restrict__ scs,
                                              const float* __restrict__ scd, const int* __restrict__ indptr,
                                              const int* __restrict__ csr, const float* __restrict__ b1,
                                              float* __restrict__ x2, int Nn) {
    int node = (blockIdx.x * 256 + threadIdx.x) >> 6;
    int l = threadIdx.x & 63;
    if (node >= Nn) return;
    int h8 = l & 7, grp = l >> 3;
    int start = indptr[node], end = indptr[node + 1];
    float sd = scd[node * 8 + h8];

    float dsum = 0.f;
    float acc8[8] = {};
    for (int base = start; base < end; base += 64) {
        int e = base + l;
        int s64 = csr[e < end ? e : start];
        int cnt = min(64, end - base);
        int nb = (cnt + 7) >> 3;             // wave-uniform trip count
#pragma unroll
        for (int b = 0; b < 8; ++b) {
            if (b < nb) {
                int slot = base + b * 8 + grp;
                int sb = __shfl(s64, b * 8 + grp);
                float v = scs[sb * 8 + h8] + sd;
                v = v > 0.f ? v : LEAKY * v;
                float ex = (slot < end) ? __expf(v) : 0.f;
                dsum += ex;
                uint4 q = *(const uint4*)(h1 + (size_t)sb * 64 + h8 * 8);   // 8 bf16 channels
                acc8[0] += ex * bflo(q.x); acc8[1] += ex * bfhi(q.x);
                acc8[2] += ex * bflo(q.y); acc8[3] += ex * bfhi(q.y);
                acc8[4] += ex * bflo(q.z); acc8[5] += ex * bfhi(q.z);
                acc8[6] += ex * bflo(q.w); acc8[7] += ex * bfhi(q.w);
            }
        }
    }
    // reduce over edge-group axis (bits 3..5); head axis stays per-lane
#pragma unroll
    for (int o = 8; o < 64; o <<= 1) {
        dsum += __shfl_xor(dsum, o);
#pragma unroll
        for (int k = 0; k < 8; ++k) acc8[k] += __shfl_xor(acc8[k], o);
    }
    if (grp == 0) {                      // lanes 0..7: h8 = l, write channels 8l..8l+7
        float inv = 1.f / (dsum + 1e-16f);
        float4 ba = *((const float4*)b1 + h8 * 2);
        float4 bb = *((const float4*)b1 + h8 * 2 + 1);
        float o0 = acc8[0] * inv + ba.x, o1 = acc8[1] * inv + ba.y;
        float o2 = acc8[2] * inv + ba.z, o3 = acc8[3] * inv + ba.w;
        float o4 = acc8[4] * inv + bb.x, o5 = acc8[5] * inv + bb.y;
        float o6 = acc8[6] * inv + bb.z, o7 = acc8[7] * inv + bb.w;
        o0 = o0 > 0.f ? o0 : expm1f(o0); o1 = o1 > 0.f ? o1 : expm1f(o1);
        o2 = o2 > 0.f ? o2 : expm1f(o2); o3 = o3 > 0.f ? o3 : expm1f(o3);
        o4 = o4 > 0.f ? o4 : expm1f(o4); o5 = o5 > 0.f ? o5 : expm1f(o5);
        o6 = o6 > 0.f ? o6 : expm1f(o6); o7 = o7 > 0.f ? o7 : expm1f(o7);
        float* dst = x2 + (size_t)node * 64 + h8 * 8;
        *(float4*)dst = make_float4(o0, o1, o2, o3);
        *(float4*)(dst + 4) = make_float4(o4, o5, o6, o7);
    }
}

// ---------------------------------------------------------------- conv2 aggregation (1 head) -> log_softmax -> out
// NO-MAX softmax; log_softmax keeps its own max. R3 flat form.
__global__ __launch_bounds__(256) void k_agg2(const unsigned short* __restrict__ h2, const float* __restrict__ scs,
                                              const float* __restrict__ scd, const int* __restrict__ indptr,
                                              const int* __restrict__ csr, const float* __restrict__ b2,
                                              float* __restrict__ out, int Nn) {
    int node = (blockIdx.x * 256 + threadIdx.x) >> 6;
    int l = threadIdx.x & 63;
    if (node >= Nn) return;
    int g = l >> 3, c8 = l & 7;
    int start = indptr[node], end = indptr[node + 1];
    float sd = scd[node];

    float dsum = 0.f;
    float acc8[8] = {};
    for (int base = start; base < end; base += 64) {
        int e = base + l;
        int s64 = csr[e < end ? e : start];
        float v = scs[s64] + sd;
        v = v > 0.f ? v : LEAKY * v;
        float ex = (e < end) ? __expf(v) : 0.f;
        dsum += ex;
        int cnt = min(64, end - base);
        int nb = (cnt + 7) >> 3;
#pragma unroll 2
        for (int b = 0; b < nb; ++b) {
            float exv = __shfl(ex, b * 8 + g);
            int sb = __shfl(s64, b * 8 + g);
            uint4 q = *(const uint4*)(h2 + (size_t)sb * 64 + c8 * 8);
            acc8[0] += exv * bflo(q.x); acc8[1] += exv * bfhi(q.x);
            acc8[2] += exv * bflo(q.y); acc8[3] += exv * bfhi(q.y);
            acc8[4] += exv * bflo(q.z); acc8[5] += exv * bfhi(q.z);
            acc8[6] += exv * bflo(q.w); acc8[7] += exv * bfhi(q.w);
        }
    }
#pragma unroll
    for (int o = 32; o; o >>= 1) dsum += __shfl_xor(dsum, o);   // full reduce
#pragma unroll
    for (int o = 8; o < 64; o <<= 1)
#pragma unroll
        for (int k = 0; k < 8; ++k) acc8[k] += __shfl_xor(acc8[k], o);

    float inv = 1.f / (dsum + 1e-16f);
    float4 ba = *((const float4*)b2 + c8 * 2);
    float4 bb = *((const float4*)b2 + c8 * 2 + 1);
    float ov[8];
    ov[0] = acc8[0] * inv + ba.x; ov[1] = acc8[1] * inv + ba.y;
    ov[2] = acc8[2] * inv + ba.z; ov[3] = acc8[3] * inv + ba.w;
    ov[4] = acc8[4] * inv + bb.x; ov[5] = acc8[5] * inv + bb.y;
    ov[6] = acc8[6] * inv + bb.z; ov[7] = acc8[7] * inv + bb.w;

    // log_softmax over 64 channels: local max/sum over 8, xor-reduce over c8 axis (bits 0..2)
    float m2 = ov[0];
#pragma unroll
    for (int k = 1; k < 8; ++k) m2 = fmaxf(m2, ov[k]);
#pragma unroll
    for (int o = 1; o < 8; o <<= 1) m2 = fmaxf(m2, __shfl_xor(m2, o));
    float se = 0.f;
#pragma unroll
    for (int k = 0; k < 8; ++k) se += __expf(ov[k] - m2);
#pragma unroll
    for (int o = 1; o < 8; o <<= 1) se += __shfl_xor(se, o);
    float ls = m2 + __logf(se);
    if (g == 0) {                        // lanes 0..7: c8 = l, write channels 8l..8l+7
        float* dst = out + (size_t)node * 64 + c8 * 8;
        *(float4*)dst = make_float4(ov[0] - ls, ov[1] - ls, ov[2] - ls, ov[3] - ls);
        *(float4*)(dst + 4) = make_float4(ov[4] - ls, ov[5] - ls, ov[6] - ls, ov[7] - ls);
    }
}

// ---------------------------------------------------------------- launch
extern "C" void kernel_launch(void* const* d_in, const int* in_sizes, int n_in,
                              void* d_out, int out_size, void* d_ws, size_t ws_size,
                              hipStream_t stream) {
    (void)n_in; (void)out_size; (void)ws_size;
    const float* x   = (const float*)d_in[0];
    const int*   ei  = (const int*)d_in[1];
    const float* W1  = (const float*)d_in[2];
    const float* as1 = (const float*)d_in[3];
    const float* ad1 = (const float*)d_in[4];
    const float* b1  = (const float*)d_in[5];
    const float* W2  = (const float*)d_in[6];
    const float* as2 = (const float*)d_in[7];
    const float* ad2 = (const float*)d_in[8];
    const float* b2  = (const float*)d_in[9];
    float* out = (float*)d_out;

    const int N = in_sizes[0] / 512;
    const int E = in_sizes[1] / 2;

    char* p = (char*)d_ws;
    auto alloc = [&](size_t bytes) -> char* {
        char* r = p; p += (bytes + 255) & ~(size_t)255; return r;
    };
    unsigned short* h1bf = (unsigned short*)alloc((size_t)N * 64 * 2);
    float* x2    = (float*)alloc((size_t)N * 64 * 4);
    unsigned short* h2bf = h1bf;       // overlay: h1bf dead after k_agg1
    float* sc1s  = (float*)alloc((size_t)N * 8 * 4);
    float* sc1d  = (float*)alloc((size_t)N * 8 * 4);
    float* sc2s  = (float*)alloc((size_t)N * 4);
    float* sc2d  = (float*)alloc((size_t)N * 4);
    int*   deg   = (int*)alloc((size_t)N * 4);
    int*   deg8  = (int*)alloc((size_t)N * 8 * 4);
    int*   cursor8 = (int*)alloc((size_t)N * 8 * 4);
    int*   indptr= (int*)alloc((size_t)(N + 1) * 4);
    int*   csr   = (int*)alloc((size_t)(E + N) * 4);
    int*   bsum  = (int*)alloc(64 * 4);
    unsigned short* W1t = (unsigned short*)alloc(64 * 512 * 2);

    const int B = (N + CHUNK - 1) / CHUNK;     // 49 <= 64
    const int G1 = (N + 127) / 128;            // gemm1 blocks in mega1

    // init (W1t prep + deg8 zero, merged)
    const long long miscElems = (64 * 512 > 8 * (long long)N) ? 64 * 512 : 8 * (long long)N;
    k_misc<<<(int)((miscElems + 255) / 256), 256, 0, stream>>>(W1, W1t, deg8, N);

    // MEGA1: conv1 GEMM (+fused sc1) || privatized edge count — overlapped (R8 best)
    k_mega1<<<G1 + 1024, 256, 0, stream>>>(x, W1t, h1bf, as1, ad1, sc1s, sc1d, N,
                                           ei, deg8, E, G1);

    // CSR build: fold -> indptr+cursor8+self-loops -> single-pass privatized fill
    k_scan1   <<<B, 256, 0, stream>>>(deg8, deg, bsum, N);
    k_scan3   <<<B, 256, 0, stream>>>(deg, deg8, bsum, indptr, cursor8, csr, N, B);
    k_fill_priv<<<1024, 256, 0, stream>>>(ei, cursor8, csr, E, N);

    // conv1 aggregation
    k_agg1<<<(N + 3) / 4, 256, 0, stream>>>(h1bf, sc1s, sc1d, indptr, csr, b1, x2, N);

    // conv2 (fp32 GEMM -> bf16 h2, scores fused)
    gemm_n64<64><<<(N + 63) / 64, 256, 0, stream>>>(x2, W2, h2bf, as2, ad2, sc2s, sc2d, N, 64);

    // conv2 aggregation -> log_softmax -> out
    k_agg2<<<(N + 3) / 4, 256, 0, stream>>>(h2bf, sc2s, sc2d, indptr, csr, b2, out, N);
}

// Round 11
// 558.204 us; speedup vs baseline: 1.0452x; 1.0452x over previous
//
#include <hip/hip_runtime.h>
#include <cstdint>
#include <cstddef>

// Problem constants (from reference): IN=512, H=8, C=8, HID=64, OUT=64
#define LEAKY 0.2f
#define NEG_INF -3.402823466e38f
static const int CHUNK = 2048;   // scan chunk per block (256 thr * 8)

typedef __attribute__((ext_vector_type(8))) short short8;
typedef __attribute__((ext_vector_type(4))) float floatx4;

__device__ __forceinline__ unsigned short f2bf(float f) {   // RNE float->bf16
    unsigned u = __float_as_uint(f);
    u += 0x7fffu + ((u >> 16) & 1u);
    return (unsigned short)(u >> 16);
}
__device__ __forceinline__ float bf2f(unsigned short u) {
    return __uint_as_float(((unsigned)u) << 16);
}
__device__ __forceinline__ float bflo(unsigned u) { return __uint_as_float(u << 16); }
__device__ __forceinline__ float bfhi(unsigned u) { return __uint_as_float(u & 0xffff0000u); }

// ---------------------------------------------------------------- misc init: W1t prep + deg8 zero (merged dispatch)
__global__ __launch_bounds__(256) void k_misc(const float* __restrict__ W1, unsigned short* __restrict__ W1t,
                                              int* __restrict__ deg8, int Nn) {
    int i = blockIdx.x * 256 + threadIdx.x;
    if (i < 64 * 512) {
        int n = i >> 9, k = i & 511;
        W1t[i] = f2bf(W1[k * 64 + n]);           // coalesced write, cached read
    }
    if (i < 8 * Nn) deg8[i] = 0;                 // privatized histograms
}

// ---------------------------------------------------------------- MEGA1: gemm1 (blocks [0,G1)) || edge count (blocks [G1,G1+1024))
// R8 structure exactly (best measured). gemm1: h1bf[M,64] = bf16(x[M,512]@W1)
// + fused sc1. As+Bs LDS double-buffered, load-early/LDS-write-late, ONE
// barrier per K-step. count: 8-way privatized histograms (XCD-local atomics).
__global__ __launch_bounds__(256) void k_mega1(const float* __restrict__ A, const unsigned short* __restrict__ W1t,
                                               unsigned short* __restrict__ C,
                                               const float* __restrict__ as1, const float* __restrict__ ad1,
                                               float* __restrict__ scs, float* __restrict__ scd, int M,
                                               const int* __restrict__ ei, int* __restrict__ deg8, int E, int G1) {
    __shared__ __align__(16) unsigned short As[2][128][40];   // 2 x 10KB, 80B row stride
    __shared__ __align__(16) unsigned short Bs[2][64][40];    // 2 x  5KB

    if ((int)blockIdx.x >= G1) {
        // ---- edge-count branch: one pass, privatized histogram
        int cb = blockIdx.x - G1;                // 0..1023
        int nthr = 1024 * 256;
        int tid = cb * 256 + threadIdx.x;
        int* mydeg = deg8 + (size_t)(cb & 7) * M;
        for (int e = tid; e < E; e += nthr) {
            int d = ei[E + e];
            atomicAdd(&mydeg[d], 1);
        }
        return;
    }

    // ---- GEMM branch
    int t = threadIdx.x;
    int w = t >> 6, l = t & 63;
    int quad = l >> 4, lm = l & 15;
    int row0 = blockIdx.x * 128;

    // staging addresses (fixed per thread)
    const float* aptr[4];
#pragma unroll
    for (int j = 0; j < 4; ++j) {
        int f = t + 256 * j;
        int r = f >> 3, c4 = f & 7;
        int rg = row0 + r; if (rg >= M) rg = M - 1;
        aptr[j] = A + (size_t)rg * 512 + c4 * 4;
    }
    int bn = t >> 2, bseg = t & 3;
    const unsigned short* bptr = W1t + (size_t)bn * 512 + bseg * 8;
    int sr = t >> 3, sc4 = t & 7;          // LDS store coords

    floatx4 acc[2][4] = {};
    float4 va[4];
    uint4 vb;

    // prologue: tile 0 -> regs -> LDS[0]
#pragma unroll
    for (int j = 0; j < 4; ++j) va[j] = *(const float4*)(aptr[j] + 0);
    vb = *(const uint4*)(bptr + 0);
#pragma unroll
    for (int j = 0; j < 4; ++j) {
        ushort4 b; b.x = f2bf(va[j].x); b.y = f2bf(va[j].y); b.z = f2bf(va[j].z); b.w = f2bf(va[j].w);
        *(ushort4*)&As[0][sr + 32 * j][sc4 * 4] = b;
    }
    *(uint4*)&Bs[0][bn][bseg * 8] = vb;
    __syncthreads();

#pragma unroll
    for (int kt = 0; kt < 16; ++kt) {
        int cur = kt & 1;
        if (kt < 15) {                       // issue next-tile global loads EARLY
            int k0 = (kt + 1) * 32;
#pragma unroll
            for (int j = 0; j < 4; ++j) va[j] = *(const float4*)(aptr[j] + k0);
            vb = *(const uint4*)(bptr + k0);
        }

        short8 af[2], bfm[4];
#pragma unroll
        for (int tm = 0; tm < 2; ++tm) {
            int m = w * 32 + tm * 16 + lm;
            af[tm] = *(const short8*)&As[cur][m][quad * 8];
        }
#pragma unroll
        for (int tn = 0; tn < 4; ++tn) {
            int n = tn * 16 + lm;
            bfm[tn] = *(const short8*)&Bs[cur][n][quad * 8];
        }
#pragma unroll
        for (int tm = 0; tm < 2; ++tm)
#pragma unroll
            for (int tn = 0; tn < 4; ++tn)
                acc[tm][tn] = __builtin_amdgcn_mfma_f32_16x16x32_bf16(af[tm], bfm[tn], acc[tm][tn], 0, 0, 0);

        if (kt < 15) {                       // LDS-write LATE (after MFMA issue)
            int nxt = cur ^ 1;
#pragma unroll
            for (int j = 0; j < 4; ++j) {
                ushort4 b; b.x = f2bf(va[j].x); b.y = f2bf(va[j].y); b.z = f2bf(va[j].z); b.w = f2bf(va[j].w);
                *(ushort4*)&As[nxt][sr + 32 * j][sc4 * 4] = b;
            }
            *(uint4*)&Bs[nxt][bn][bseg * 8] = vb;
        }
        __syncthreads();                     // single barrier per K-step
    }

    // per-lane attention-vector entries: col = tn*16+lm, head = col>>3 = tn*2 + (lm>>3)
    float as_l[4], ad_l[4];
#pragma unroll
    for (int tn = 0; tn < 4; ++tn) { as_l[tn] = as1[tn * 16 + lm]; ad_l[tn] = ad1[tn * 16 + lm]; }
    int hbase = (l >> 3) & 1;

    // epilogue: C/D layout col=lane&15, row=quad*4+reg ; emit bf16 + scores
#pragma unroll
    for (int tm = 0; tm < 2; ++tm) {
#pragma unroll
        for (int r = 0; r < 4; ++r) {
            int row = row0 + w * 32 + tm * 16 + quad * 4 + r;
            if (row < M) {
#pragma unroll
                for (int tn = 0; tn < 4; ++tn)
                    C[(size_t)row * 64 + tn * 16 + lm] = f2bf(acc[tm][tn][r]);
                // fused half-scores: per-head dot over the 8 channels (reduce lm&7 axis)
                float ps[4], pd[4];
#pragma unroll
                for (int tn = 0; tn < 4; ++tn) {
                    ps[tn] = acc[tm][tn][r] * as_l[tn];
                    pd[tn] = acc[tm][tn][r] * ad_l[tn];
                }
#pragma unroll
                for (int o = 1; o < 8; o <<= 1) {
#pragma unroll
                    for (int tn = 0; tn < 4; ++tn) {
                        ps[tn] += __shfl_xor(ps[tn], o);
                        pd[tn] += __shfl_xor(pd[tn], o);
                    }
                }
                if ((l & 7) == 0) {
#pragma unroll
                    for (int tn = 0; tn < 4; ++tn) {
                        scs[(size_t)row * 8 + tn * 2 + hbase] = ps[tn];
                        scd[(size_t)row * 8 + tn * 2 + hbase] = pd[tn];
                    }
                }
            }
        }
    }
}

// fold deg8 -> deg (+1 self-loop), produce block sums
__global__ __launch_bounds__(256) void k_scan1(const int* __restrict__ deg8, int* __restrict__ deg,
                                               int* __restrict__ bsum, int Nn) {
    __shared__ int sm[256];
    int b = blockIdx.x, t = threadIdx.x;
    int s = 0;
    int i0 = b * CHUNK + t * 8;
#pragma unroll
    for (int j = 0; j < 8; ++j) {
        int i = i0 + j;
        if (i < Nn) {
            int d = 1;
#pragma unroll
            for (int p = 0; p < 8; ++p) d += deg8[(size_t)p * Nn + i];
            deg[i] = d;
            s += d;
        }
    }
    sm[t] = s;
    __syncthreads();
    for (int o = 128; o; o >>= 1) { if (t < o) sm[t] += sm[t + o]; __syncthreads(); }
    if (t == 0) bsum[b] = sm[0];
}

// scan3: indptr + cursor (self-loop pre-written at slot indptr[i], cursor starts at +1)
__global__ __launch_bounds__(256) void k_scan3(const int* __restrict__ deg, const int* __restrict__ bsum,
                                               int* __restrict__ indptr, int* __restrict__ cursor,
                                               int* __restrict__ csr, int Nn, int B) {
    __shared__ int wsum[4];
    int b = blockIdx.x, t = threadIdx.x, lane = t & 63, w = t >> 6;

    int vb = (lane < B) ? bsum[lane] : 0;
    int incb = vb;
#pragma unroll
    for (int o = 1; o < 64; o <<= 1) { int u = __shfl_up(incb, o); if (lane >= o) incb += u; }
    int bpre_b = __shfl(incb - vb, b);       // exclusive prefix at block b

    int i0 = b * CHUNK + t * 8;
    int d[8]; int s = 0;
#pragma unroll
    for (int j = 0; j < 8; ++j) { int i = i0 + j; d[j] = (i < Nn) ? deg[i] : 0; s += d[j]; }
    int inc = s;
#pragma unroll
    for (int o = 1; o < 64; o <<= 1) { int u = __shfl_up(inc, o); if (lane >= o) inc += u; }
    if (lane == 63) wsum[w] = inc;
    __syncthreads();
    int wofs = 0;
    for (int k = 0; k < w; ++k) wofs += wsum[k];
    int base = bpre_b + wofs + (inc - s);
    int run = 0;
#pragma unroll
    for (int j = 0; j < 8; ++j) {
        int i = i0 + j;
        if (i < Nn) {
            int v = base + run;
            indptr[i] = v;
            csr[v] = i;                      // self-loop occupies first slot
            cursor[i] = v + 1;
            run += d[j];
            if (i == Nn - 1) indptr[Nn] = v + d[j];
        }
    }
}

// XCD-partitioned fill (R8 form): partition by DESTINATION range so cursor
// atomics AND csr writes stay in one XCD's L2 region (R10's edge-ownership
// split scattered csr writes across XCDs: WRITE_SIZE 101MB, 3x slower).
__global__ __launch_bounds__(256) void k_fill_p(const int* __restrict__ ei, int* __restrict__ cursor,
                                                int* __restrict__ csr, int E, int Nn) {
    int part = blockIdx.x & 7;
    int lo = (int)((long long)Nn * part >> 3);
    int hi = (int)((long long)Nn * (part + 1) >> 3);
    int nthr = (gridDim.x >> 3) * 256;
    int tid = (blockIdx.x >> 3) * 256 + threadIdx.x;
    for (int e = tid; e < E; e += nthr) {
        int d = ei[E + e];
        if (d >= lo && d < hi) {
            int s = ei[e];
            int slot = atomicAdd(&cursor[d], 1);
            csr[slot] = s;
        }
    }
}

// ---------------------------------------------------------------- SGEMM Cbf[M,64] = bf16(A[M,K] @ B[K,64]) (fp32 math, conv2)
// + fused conv2 half-scores from fp32 accumulators.
template <int KB>
__global__ __launch_bounds__(256) void gemm_n64(const float* __restrict__ A, const float* __restrict__ B,
                                                unsigned short* __restrict__ C,
                                                const float* __restrict__ as2, const float* __restrict__ ad2,
                                                float* __restrict__ sc2s, float* __restrict__ sc2d,
                                                int M, int K) {
    __shared__ float As[KB][68];
    __shared__ float Bs[KB][68];
    int tid = threadIdx.x;
    int row0 = blockIdx.x * 64;
    int tx = tid & 15, ty = tid >> 4;
    float acc[4][4] = {};
    for (int k0 = 0; k0 < K; k0 += KB) {
#pragma unroll
        for (int j = 0; j < (64 * KB) / (256 * 4); ++j) {
            int f = tid + 256 * j;
            int r = f / (KB / 4);
            int c4 = f % (KB / 4);
            int rg = row0 + r; if (rg >= M) rg = M - 1;
            float4 v = *(const float4*)(A + (size_t)rg * K + k0 + c4 * 4);
            As[c4 * 4 + 0][r] = v.x; As[c4 * 4 + 1][r] = v.y;
            As[c4 * 4 + 2][r] = v.z; As[c4 * 4 + 3][r] = v.w;
        }
#pragma unroll
        for (int j = 0; j < (KB * 64) / (256 * 4); ++j) {
            int f = tid + 256 * j;
            int kk = f / 16, c4 = f % 16;
            *(float4*)&Bs[kk][c4 * 4] = *(const float4*)(B + (size_t)(k0 + kk) * 64 + c4 * 4);
        }
        __syncthreads();
#pragma unroll
        for (int kk = 0; kk < KB; ++kk) {
            float4 a = *(const float4*)&As[kk][ty * 4];
            float4 b = *(const float4*)&Bs[kk][tx * 4];
            float av[4] = {a.x, a.y, a.z, a.w};
            float bv[4] = {b.x, b.y, b.z, b.w};
#pragma unroll
            for (int i = 0; i < 4; ++i)
#pragma unroll
                for (int j = 0; j < 4; ++j) acc[i][j] += av[i] * bv[j];
        }
        __syncthreads();
    }
    float as_l[4], ad_l[4];
#pragma unroll
    for (int j = 0; j < 4; ++j) { as_l[j] = as2[tx * 4 + j]; ad_l[j] = ad2[tx * 4 + j]; }
#pragma unroll
    for (int i = 0; i < 4; ++i) {
        int rg = row0 + ty * 4 + i;
        if (rg < M) {
            ushort4 b; b.x = f2bf(acc[i][0]); b.y = f2bf(acc[i][1]);
            b.z = f2bf(acc[i][2]); b.w = f2bf(acc[i][3]);
            *(ushort4*)(C + (size_t)rg * 64 + tx * 4) = b;
            // fused full-row score dot: reduce over tx axis (lane bits 0..3)
            float ps = acc[i][0] * as_l[0] + acc[i][1] * as_l[1] + acc[i][2] * as_l[2] + acc[i][3] * as_l[3];
            float pd = acc[i][0] * ad_l[0] + acc[i][1] * ad_l[1] + acc[i][2] * ad_l[2] + acc[i][3] * ad_l[3];
#pragma unroll
            for (int o = 1; o < 16; o <<= 1) { ps += __shfl_xor(ps, o); pd += __shfl_xor(pd, o); }
            if (tx == 0) { sc2s[rg] = ps; sc2d[rg] = pd; }
        }
    }
}

// ---------------------------------------------------------------- conv1 aggregation (8 heads x 8 ch) -> elu -> x2
// PERSISTENT grid-stride waves: R8 counters showed ~51% occupancy with a
// ~100% cap and 25k short-lived blocks (avg 3 inner iterations) -> block
// launch/drain bound. 2048 blocks, each wave strides over nodes. Inner loop
// unchanged (R3 flat form; batching regressed twice).
__global__ __launch_bounds__(256) void k_agg1(const unsigned short* __restrict__ h1, const float* __restrict__ scs,
                                              const float* __restrict__ scd, const int* __restrict__ indptr,
                                              const int* __restrict__ csr, const float* __restrict__ b1,
                                              float* __restrict__ x2, int Nn) {
    int wid = (blockIdx.x * 256 + threadIdx.x) >> 6;
    int nw = (gridDim.x * 256) >> 6;
    int l = threadIdx.x & 63;
    int h8 = l & 7, grp = l >> 3;

    for (int node = wid; node < Nn; node += nw) {
        int start = indptr[node], end = indptr[node + 1];
        float sd = scd[node * 8 + h8];

        float dsum = 0.f;
        float acc8[8] = {};
        for (int base = start; base < end; base += 64) {
            int e = base + l;
            int s64 = csr[e < end ? e : start];
            int cnt = min(64, end - base);
            int nb = (cnt + 7) >> 3;             // wave-uniform trip count
#pragma unroll
            for (int b = 0; b < 8; ++b) {
                if (b < nb) {
                    int slot = base + b * 8 + grp;
                    int sb = __shfl(s64, b * 8 + grp);
                    float v = scs[sb * 8 + h8] + sd;
                    v = v > 0.f ? v : LEAKY * v;
                    float ex = (slot < end) ? __expf(v) : 0.f;
                    dsum += ex;
                    uint4 q = *(const uint4*)(h1 + (size_t)sb * 64 + h8 * 8);   // 8 bf16 channels
                    acc8[0] += ex * bflo(q.x); acc8[1] += ex * bfhi(q.x);
                    acc8[2] += ex * bflo(q.y); acc8[3] += ex * bfhi(q.y);
                    acc8[4] += ex * bflo(q.z); acc8[5] += ex * bfhi(q.z);
                    acc8[6] += ex * bflo(q.w); acc8[7] += ex * bfhi(q.w);
                }
            }
        }
        // reduce over edge-group axis (bits 3..5); head axis stays per-lane
#pragma unroll
        for (int o = 8; o < 64; o <<= 1) {
            dsum += __shfl_xor(dsum, o);
#pragma unroll
            for (int k = 0; k < 8; ++k) acc8[k] += __shfl_xor(acc8[k], o);
        }
        if (grp == 0) {                      // lanes 0..7: h8 = l, write channels 8l..8l+7
            float inv = 1.f / (dsum + 1e-16f);
            float4 ba = *((const float4*)b1 + h8 * 2);
            float4 bb = *((const float4*)b1 + h8 * 2 + 1);
            float o0 = acc8[0] * inv + ba.x, o1 = acc8[1] * inv + ba.y;
            float o2 = acc8[2] * inv + ba.z, o3 = acc8[3] * inv + ba.w;
            float o4 = acc8[4] * inv + bb.x, o5 = acc8[5] * inv + bb.y;
            float o6 = acc8[6] * inv + bb.z, o7 = acc8[7] * inv + bb.w;
            o0 = o0 > 0.f ? o0 : expm1f(o0); o1 = o1 > 0.f ? o1 : expm1f(o1);
            o2 = o2 > 0.f ? o2 : expm1f(o2); o3 = o3 > 0.f ? o3 : expm1f(o3);
            o4 = o4 > 0.f ? o4 : expm1f(o4); o5 = o5 > 0.f ? o5 : expm1f(o5);
            o6 = o6 > 0.f ? o6 : expm1f(o6); o7 = o7 > 0.f ? o7 : expm1f(o7);
            float* dst = x2 + (size_t)node * 64 + h8 * 8;
            *(float4*)dst = make_float4(o0, o1, o2, o3);
            *(float4*)(dst + 4) = make_float4(o4, o5, o6, o7);
        }
    }
}

// ---------------------------------------------------------------- conv2 aggregation (1 head) -> log_softmax -> out
// PERSISTENT grid-stride waves (same rationale as k_agg1).
__global__ __launch_bounds__(256) void k_agg2(const unsigned short* __restrict__ h2, const float* __restrict__ scs,
                                              const float* __restrict__ scd, const int* __restrict__ indptr,
                                              const int* __restrict__ csr, const float* __restrict__ b2,
                                              float* __restrict__ out, int Nn) {
    int wid = (blockIdx.x * 256 + threadIdx.x) >> 6;
    int nw = (gridDim.x * 256) >> 6;
    int l = threadIdx.x & 63;
    int g = l >> 3, c8 = l & 7;

    for (int node = wid; node < Nn; node += nw) {
        int start = indptr[node], end = indptr[node + 1];
        float sd = scd[node];

        float dsum = 0.f;
        float acc8[8] = {};
        for (int base = start; base < end; base += 64) {
            int e = base + l;
            int s64 = csr[e < end ? e : start];
            float v = scs[s64] + sd;
            v = v > 0.f ? v : LEAKY * v;
            float ex = (e < end) ? __expf(v) : 0.f;
            dsum += ex;
            int cnt = min(64, end - base);
            int nb = (cnt + 7) >> 3;
#pragma unroll 2
            for (int b = 0; b < nb; ++b) {
                float exv = __shfl(ex, b * 8 + g);
                int sb = __shfl(s64, b * 8 + g);
                uint4 q = *(const uint4*)(h2 + (size_t)sb * 64 + c8 * 8);
                acc8[0] += exv * bflo(q.x); acc8[1] += exv * bfhi(q.x);
                acc8[2] += exv * bflo(q.y); acc8[3] += exv * bfhi(q.y);
                acc8[4] += exv * bflo(q.z); acc8[5] += exv * bfhi(q.z);
                acc8[6] += exv * bflo(q.w); acc8[7] += exv * bfhi(q.w);
            }
        }
#pragma unroll
        for (int o = 32; o; o >>= 1) dsum += __shfl_xor(dsum, o);   // full reduce
#pragma unroll
        for (int o = 8; o < 64; o <<= 1)
#pragma unroll
            for (int k = 0; k < 8; ++k) acc8[k] += __shfl_xor(acc8[k], o);

        float inv = 1.f / (dsum + 1e-16f);
        float4 ba = *((const float4*)b2 + c8 * 2);
        float4 bb = *((const float4*)b2 + c8 * 2 + 1);
        float ov[8];
        ov[0] = acc8[0] * inv + ba.x; ov[1] = acc8[1] * inv + ba.y;
        ov[2] = acc8[2] * inv + ba.z; ov[3] = acc8[3] * inv + ba.w;
        ov[4] = acc8[4] * inv + bb.x; ov[5] = acc8[5] * inv + bb.y;
        ov[6] = acc8[6] * inv + bb.z; ov[7] = acc8[7] * inv + bb.w;

        // log_softmax over 64 channels: local max/sum over 8, xor-reduce over c8 axis (bits 0..2)
        float m2 = ov[0];
#pragma unroll
        for (int k = 1; k < 8; ++k) m2 = fmaxf(m2, ov[k]);
#pragma unroll
        for (int o = 1; o < 8; o <<= 1) m2 = fmaxf(m2, __shfl_xor(m2, o));
        float se = 0.f;
#pragma unroll
        for (int k = 0; k < 8; ++k) se += __expf(ov[k] - m2);
#pragma unroll
        for (int o = 1; o < 8; o <<= 1) se += __shfl_xor(se, o);
        float ls = m2 + __logf(se);
        if (g == 0) {                        // lanes 0..7: c8 = l, write channels 8l..8l+7
            float* dst = out + (size_t)node * 64 + c8 * 8;
            *(float4*)dst = make_float4(ov[0] - ls, ov[1] - ls, ov[2] - ls, ov[3] - ls);
            *(float4*)(dst + 4) = make_float4(ov[4] - ls, ov[5] - ls, ov[6] - ls, ov[7] - ls);
        }
    }
}

// ---------------------------------------------------------------- launch
extern "C" void kernel_launch(void* const* d_in, const int* in_sizes, int n_in,
                              void* d_out, int out_size, void* d_ws, size_t ws_size,
                              hipStream_t stream) {
    (void)n_in; (void)out_size; (void)ws_size;
    const float* x   = (const float*)d_in[0];
    const int*   ei  = (const int*)d_in[1];
    const float* W1  = (const float*)d_in[2];
    const float* as1 = (const float*)d_in[3];
    const float* ad1 = (const float*)d_in[4];
    const float* b1  = (const float*)d_in[5];
    const float* W2  = (const float*)d_in[6];
    const float* as2 = (const float*)d_in[7];
    const float* ad2 = (const float*)d_in[8];
    const float* b2  = (const float*)d_in[9];
    float* out = (float*)d_out;

    const int N = in_sizes[0] / 512;
    const int E = in_sizes[1] / 2;

    char* p = (char*)d_ws;
    auto alloc = [&](size_t bytes) -> char* {
        char* r = p; p += (bytes + 255) & ~(size_t)255; return r;
    };
    unsigned short* h1bf = (unsigned short*)alloc((size_t)N * 64 * 2);
    float* x2    = (float*)alloc((size_t)N * 64 * 4);
    unsigned short* h2bf = h1bf;       // overlay: h1bf dead after k_agg1
    float* sc1s  = (float*)alloc((size_t)N * 8 * 4);
    float* sc1d  = (float*)alloc((size_t)N * 8 * 4);
    float* sc2s  = (float*)alloc((size_t)N * 4);
    float* sc2d  = (float*)alloc((size_t)N * 4);
    int*   deg   = (int*)alloc((size_t)N * 4);
    int*   deg8  = (int*)alloc((size_t)N * 8 * 4);
    int*   cursor= (int*)alloc((size_t)N * 4);
    int*   indptr= (int*)alloc((size_t)(N + 1) * 4);
    int*   csr   = (int*)alloc((size_t)(E + N) * 4);
    int*   bsum  = (int*)alloc(64 * 4);
    unsigned short* W1t = (unsigned short*)alloc(64 * 512 * 2);

    const int B = (N + CHUNK - 1) / CHUNK;     // 49 <= 64
    const int G1 = (N + 127) / 128;            // gemm1 blocks in mega1

    // init (W1t prep + deg8 zero, merged)
    const long long miscElems = (64 * 512 > 8 * (long long)N) ? 64 * 512 : 8 * (long long)N;
    k_misc<<<(int)((miscElems + 255) / 256), 256, 0, stream>>>(W1, W1t, deg8, N);

    // MEGA1: conv1 GEMM (+fused sc1) || privatized edge count — overlapped (R8 best)
    k_mega1<<<G1 + 1024, 256, 0, stream>>>(x, W1t, h1bf, as1, ad1, sc1s, sc1d, N,
                                           ei, deg8, E, G1);

    // CSR build: fold -> indptr+cursor(+self-loops) -> dst-partitioned fill
    k_scan1 <<<B, 256, 0, stream>>>(deg8, deg, bsum, N);
    k_scan3 <<<B, 256, 0, stream>>>(deg, bsum, indptr, cursor, csr, N, B);
    k_fill_p<<<1024, 256, 0, stream>>>(ei, cursor, csr, E, N);

    // conv1 aggregation (persistent)
    k_agg1<<<2048, 256, 0, stream>>>(h1bf, sc1s, sc1d, indptr, csr, b1, x2, N);

    // conv2 (fp32 GEMM -> bf16 h2, scores fused)
    gemm_n64<64><<<(N + 63) / 64, 256, 0, stream>>>(x2, W2, h2bf, as2, ad2, sc2s, sc2d, N, 64);

    // conv2 aggregation -> log_softmax -> out (persistent)
    k_agg2<<<2048, 256, 0, stream>>>(h2bf, sc2s, sc2d, indptr, csr, b2, out, N);
}